// Round 1
// baseline (832.784 us; speedup 1.0000x reference)
//
#include <hip/hip_runtime.h>

typedef unsigned short u16;
typedef __attribute__((ext_vector_type(4))) float f32x4;
typedef __attribute__((ext_vector_type(4))) unsigned int u32x4;
typedef __attribute__((ext_vector_type(2))) unsigned int u32x2;
typedef __attribute__((ext_vector_type(8))) __bf16 bf16x8;

#define NB 16
#define NC 256
#define ND 64
#define NPIX 16384

// ---- workspace layout (float offsets) ----
static constexpr size_t O_GX   = 0;                               // [16][256][256] f32 Gram
static constexpr size_t O_SX   = O_GX + (size_t)NB*NC*NC;         // [16][256] col sums
static constexpr size_t O_AQ   = O_SX + (size_t)NB*NC;            // Aq [64][256]
static constexpr size_t O_AKT  = O_AQ + (size_t)ND*NC;            // Ak^T [256][64]
static constexpr size_t O_AV   = O_AKT + (size_t)NC*ND;           // Av [64][256]
static constexpr size_t O_BQ   = O_AV + (size_t)ND*NC;            // beta_q [64]
static constexpr size_t O_BK   = O_BQ + ND;
static constexpr size_t O_BV   = O_BK + ND;
static constexpr size_t O_S1   = O_BV + ND;                       // S1 [16][64][256]
static constexpr size_t O_TQ   = O_S1 + (size_t)NB*ND*NC;         // [16][64]
static constexpr size_t O_TK   = O_TQ + (size_t)NB*ND;
static constexpr size_t O_SC   = O_TK + (size_t)NB*ND;            // score [16][64][64]
static constexpr size_t O_BIAS = O_SC + (size_t)NB*ND*ND;         // [16][256]
static constexpr size_t O_GB   = O_BIAS + (size_t)NB*NC;          // G bf16 [16][256][256] (u16)
static constexpr size_t O_GP   = O_GB + (size_t)NB*NC*NC/2;       // Gram partials [16][16][256][256]
static constexpr size_t GP_FLOATS = (size_t)16*NB*NC*NC;

// XOR swizzle on 16B granules within 128B rows: keeps ds_read_b128 frag reads 2-way (free)
__device__ __forceinline__ int fsw(int row) { return ((row ^ (row >> 3)) & 7) << 4; }

__device__ __forceinline__ u16 f2bf(float f) {      // RNE f32->bf16
  union { float f; unsigned u; } v; v.f = f;
  unsigned r = v.u + 0x7fffu + ((v.u >> 16) & 1u);
  return (u16)(r >> 16);
}

// ---- K0: combined weights  Aq=wq@w_in etc., betas ----
__global__ void k0_weights(const float* __restrict__ w_in, const float* __restrict__ b_in,
                           const float* __restrict__ wq, const float* __restrict__ bqv,
                           const float* __restrict__ wk, const float* __restrict__ bkv,
                           const float* __restrict__ wv, const float* __restrict__ bvv,
                           float* __restrict__ ws) {
  const int m = blockIdx.x >> 2, cc = blockIdx.x & 3;
  const float* w = (m == 0) ? wq : (m == 1) ? wk : wv;
  const int t = threadIdx.x;
  const int i = t >> 2;
  const int c0 = cc*64 + (t & 3)*16;
  float acc[16];
  #pragma unroll
  for (int e = 0; e < 16; ++e) acc[e] = 0.f;
  for (int j = 0; j < 64; ++j) {
    const float wij = w[i*64 + j];
    const float* wr = w_in + (size_t)j*NC + c0;
    #pragma unroll
    for (int e = 0; e < 16; ++e) acc[e] += wij * wr[e];
  }
  if (m == 0)      { float* A = ws + O_AQ;  for (int e = 0; e < 16; ++e) A[(size_t)i*NC + c0 + e] = acc[e]; }
  else if (m == 1) { float* A = ws + O_AKT; for (int e = 0; e < 16; ++e) A[(size_t)(c0+e)*ND + i] = acc[e]; }
  else             { float* A = ws + O_AV;  for (int e = 0; e < 16; ++e) A[(size_t)i*NC + c0 + e] = acc[e]; }
  if (cc == 0 && t < 64) {
    float a = 0.f;
    for (int j = 0; j < 64; ++j) a += w[t*64 + j] * b_in[j];
    a += ((m == 0) ? bqv : (m == 1) ? bkv : bvv)[t];
    ws[((m == 0) ? O_BQ : (m == 1) ? O_BK : O_BV) + t] = a;
  }
}

// ---- K1: per-batch Gram of x (bf16 MFMA, K split 16-way) + column sums ----
template<bool PART>
__global__ __launch_bounds__(512, 2) void k1_gram(const float* __restrict__ x, float* __restrict__ ws) {
  const int b = blockIdx.x & 15, ks = blockIdx.x >> 4;
  const float* xb = x + (size_t)b*NC*NPIX + (size_t)ks*1024;
  __shared__ u16 lds[2][NC*64];
  const int t = threadIdx.x, lane = t & 63, wid = t >> 6;
  const int wr = wid >> 1, wc = wid & 1;
  const int srow = t >> 2, scol = (t & 3) * 16;
  const f32x4 vzero = {0.f, 0.f, 0.f, 0.f};

  f32x4 pf[2][4];
  float csum[2] = {0.f, 0.f};
  f32x4 acc[4][8];
  #pragma unroll
  for (int i2 = 0; i2 < 4; ++i2)
    #pragma unroll
    for (int j2 = 0; j2 < 8; ++j2) acc[i2][j2] = vzero;

  auto load_iter = [&](int it) {
    #pragma unroll
    for (int p = 0; p < 2; ++p) {
      const float* src = xb + (size_t)(srow + p*128)*NPIX + it*64 + scol;
      #pragma unroll
      for (int j = 0; j < 4; ++j) pf[p][j] = *(const f32x4*)(src + j*4);
    }
  };
  auto store_iter = [&](int buf) {
    char* base = (char*)&lds[buf][0];
    #pragma unroll
    for (int p = 0; p < 2; ++p) {
      const int row = srow + p*128;
      const int fb = fsw(row);
      u16 h[16];
      float s = 0.f;
      #pragma unroll
      for (int j = 0; j < 4; ++j)
        #pragma unroll
        for (int e = 0; e < 4; ++e) { const float v = pf[p][j][e]; s += v; h[j*4+e] = f2bf(v); }
      csum[p] += s;
      u32x4 w0, w1;
      #pragma unroll
      for (int q = 0; q < 4; ++q) w0[q] = (unsigned)h[2*q]   | ((unsigned)h[2*q+1]   << 16);
      #pragma unroll
      for (int q = 0; q < 4; ++q) w1[q] = (unsigned)h[8+2*q] | ((unsigned)h[8+2*q+1] << 16);
      *(u32x4*)(base + row*128 + ((scol*2)      ^ fb)) = w0;
      *(u32x4*)(base + row*128 + ((scol*2 + 16) ^ fb)) = w1;
    }
  };

  load_iter(0);
  store_iter(0);
  __syncthreads();
  for (int it = 0; it < 16; ++it) {
    const int cur = it & 1;
    if (it < 15) load_iter(it + 1);
    const char* base = (const char*)&lds[cur][0];
    #pragma unroll
    for (int kk = 0; kk < 2; ++kk) {
      const int kb = kk*64 + (lane >> 4) * 16;
      bf16x8 af[4], bfv[8];
      #pragma unroll
      for (int mi = 0; mi < 4; ++mi) {
        const int row = wr*64 + mi*16 + (lane & 15);
        af[mi] = *(const bf16x8*)(base + row*128 + (kb ^ fsw(row)));
      }
      #pragma unroll
      for (int ni = 0; ni < 8; ++ni) {
        const int row = wc*128 + ni*16 + (lane & 15);
        bfv[ni] = *(const bf16x8*)(base + row*128 + (kb ^ fsw(row)));
      }
      #pragma unroll
      for (int mi = 0; mi < 4; ++mi)
        #pragma unroll
        for (int ni = 0; ni < 8; ++ni)
          acc[mi][ni] = __builtin_amdgcn_mfma_f32_16x16x32_bf16(af[mi], bfv[ni], acc[mi][ni], 0, 0, 0);
    }
    if (it < 15) store_iter(cur ^ 1);
    __syncthreads();
  }

  #pragma unroll
  for (int p = 0; p < 2; ++p) {
    float s = csum[p];
    s += __shfl_xor(s, 1);
    s += __shfl_xor(s, 2);
    if ((t & 3) == 0) atomicAdd(ws + O_SX + b*NC + srow + p*128, s);
  }

  if (PART) {
    float* dst = ws + O_GP + ((size_t)ks*NB + b)*((size_t)NC*NC);
    #pragma unroll
    for (int mi = 0; mi < 4; ++mi)
      #pragma unroll
      for (int ni = 0; ni < 8; ++ni)
        #pragma unroll
        for (int e = 0; e < 4; ++e) {
          const int rr = wr*64 + mi*16 + (lane >> 4)*4 + e;
          const int dd = wc*128 + ni*16 + (lane & 15);
          dst[(size_t)rr*NC + dd] = acc[mi][ni][e];
        }
  } else {
    float* dst = ws + O_GX + (size_t)b*NC*NC;
    #pragma unroll
    for (int mi = 0; mi < 4; ++mi)
      #pragma unroll
      for (int ni = 0; ni < 8; ++ni)
        #pragma unroll
        for (int e = 0; e < 4; ++e) {
          const int rr = wr*64 + mi*16 + (lane >> 4)*4 + e;
          const int dd = wc*128 + ni*16 + (lane & 15);
          atomicAdd(dst + (size_t)rr*NC + dd, acc[mi][ni][e]);
        }
  }
}

__global__ void k1_reduce(float* __restrict__ ws) {
  const size_t idx = ((size_t)blockIdx.x * 256 + threadIdx.x) * 4;
  const f32x4 vzero = {0.f, 0.f, 0.f, 0.f};
  f32x4 a = vzero;
  #pragma unroll
  for (int ks = 0; ks < 16; ++ks)
    a += *(const f32x4*)(ws + O_GP + (size_t)ks*NB*NC*NC + idx);
  *(f32x4*)(ws + O_GX + idx) = a;
}

// ---- K2a: S1 = Aq @ Gx (fp32) + tq/tk ----
__global__ void k2_s1(float* __restrict__ ws) {
  const int b = blockIdx.x >> 2, jc = blockIdx.x & 3;
  const int t = threadIdx.x;
  const int i = t >> 3, j0 = jc*64 + (t & 7)*8;
  const float* Gx = ws + O_GX + (size_t)b*NC*NC;
  const float* Aq = ws + O_AQ;
  const f32x4 vzero = {0.f, 0.f, 0.f, 0.f};
  f32x4 a0 = vzero, a1 = vzero;
  for (int c = 0; c < 256; ++c) {
    const float a = Aq[(size_t)i*NC + c];
    const float* g = Gx + (size_t)c*NC + j0;
    a0 += a * *(const f32x4*)(g);
    a1 += a * *(const f32x4*)(g + 4);
  }
  float* s1 = ws + O_S1 + (size_t)b*ND*NC + (size_t)i*NC + j0;
  *(f32x4*)(s1) = a0; *(f32x4*)(s1 + 4) = a1;
  if (jc == 0 && t < 128) {
    const float* sxp = ws + O_SX + b*NC;
    float a = 0.f;
    if (t < 64) {
      for (int c = 0; c < 256; ++c) a += ws[O_AKT + (size_t)c*ND + t] * sxp[c];
      ws[O_TK + b*ND + t] = a;
    } else {
      const int i2 = t - 64;
      for (int c = 0; c < 256; ++c) a += ws[O_AQ + (size_t)i2*NC + c] * sxp[c];
      ws[O_TQ + b*ND + i2] = a;
    }
  }
}

// ---- K2b: score = scale*(S1 @ Ak^T + bias cross terms) ----
__global__ void k2_score(float* __restrict__ ws) {
  const int b = blockIdx.x >> 2, jc = blockIdx.x & 3;
  const int t = threadIdx.x;
  const int i = t >> 3, j = jc*16 + (t & 7)*2;
  const float* s1 = ws + O_S1 + (size_t)b*ND*NC + (size_t)i*NC;
  const float* akt = ws + O_AKT;
  float a0 = 0.f, a1 = 0.f;
  for (int d = 0; d < 256; ++d) {
    const float s = s1[d];
    a0 += s * akt[(size_t)d*ND + j];
    a1 += s * akt[(size_t)d*ND + j + 1];
  }
  const float bq = ws[O_BQ + i], tq = ws[O_TQ + b*ND + i];
  const float bk0 = ws[O_BK + j], bk1 = ws[O_BK + j + 1];
  const float tk0 = ws[O_TK + b*ND + j], tk1 = ws[O_TK + b*ND + j + 1];
  const float sc = 0.125f;  // 1/sqrt(64)
  float* so = ws + O_SC + (size_t)b*ND*ND + (size_t)i*ND + j;
  so[0] = sc*(a0 + bq*tk0 + tq*bk0 + 16384.f*bq*bk0);
  so[1] = sc*(a1 + bq*tk1 + tq*bk1 + 16384.f*bq*bk1);
}

// ---- K2c: softmax + M = w_out@attn^T + G = M@Av (bf16) + bias ----
__global__ void k2_attn_g(const float* __restrict__ w_out, const float* __restrict__ b_out,
                          float* __restrict__ ws) {
  const int b = blockIdx.x >> 2, oc = blockIdx.x & 3;
  const int t = threadIdx.x;
  __shared__ float sc[64*68];
  __shared__ float at[64*68];
  __shared__ float ml[64*68];
  #pragma unroll
  for (int k = 0; k < 8; ++k) {
    const int idx = t + k*512;
    sc[(idx >> 6)*68 + (idx & 63)] = ws[O_SC + (size_t)b*ND*ND + idx];
  }
  __syncthreads();
  if (t < 64) {
    float m = -1e30f;
    for (int j = 0; j < 64; ++j) m = fmaxf(m, sc[t*68 + j]);
    float s = 0.f;
    for (int j = 0; j < 64; ++j) { const float e = __expf(sc[t*68 + j] - m); sc[t*68 + j] = e; s += e; }
    const float inv = 1.f / s;
    for (int j = 0; j < 64; ++j) at[j*68 + t] = sc[t*68 + j] * inv;  // attn^T[j][c]
  }
  __syncthreads();
  {
    const int o = t >> 3, c0 = (t & 7)*8;
    float acc[8];
    #pragma unroll
    for (int e = 0; e < 8; ++e) acc[e] = 0.f;
    for (int j = 0; j < 64; ++j) {
      const float w = w_out[(size_t)(oc*64 + o)*ND + j];
      #pragma unroll
      for (int e = 0; e < 8; ++e) acc[e] += w * at[j*68 + c0 + e];
    }
    #pragma unroll
    for (int e = 0; e < 8; ++e) ml[o*68 + c0 + e] = acc[e];
  }
  __syncthreads();
  {
    const int c0 = (t & 15)*16;
    #pragma unroll
    for (int or2 = 0; or2 < 2; ++or2) {
      const int o = (t >> 4) + or2*32;
      float acc[16];
      #pragma unroll
      for (int e = 0; e < 16; ++e) acc[e] = 0.f;
      for (int c = 0; c < 64; ++c) {
        const float m = ml[o*68 + c];
        const float* av = ws + O_AV + (size_t)c*NC + c0;
        #pragma unroll
        for (int e = 0; e < 16; ++e) acc[e] += m * av[e];
      }
      u16* gb = (u16*)(ws + O_GB) + (size_t)b*NC*NC + (size_t)(oc*64 + o)*NC + c0;
      u16 h[16];
      #pragma unroll
      for (int e = 0; e < 16; ++e) h[e] = f2bf(acc[e]);
      u32x4 w0, w1;
      #pragma unroll
      for (int q = 0; q < 4; ++q) w0[q] = (unsigned)h[2*q]   | ((unsigned)h[2*q+1]   << 16);
      #pragma unroll
      for (int q = 0; q < 4; ++q) w1[q] = (unsigned)h[8+2*q] | ((unsigned)h[8+2*q+1] << 16);
      *(u32x4*)(gb) = w0;
      *(u32x4*)(gb + 8) = w1;
    }
  }
  if (t < 64) {
    float a = 0.f;
    for (int c = 0; c < 64; ++c) a += ml[t*68 + c] * ws[O_BV + c];
    ws[O_BIAS + b*NC + oc*64 + t] = a + b_out[oc*64 + t];
  }
}

// ---- K3: out = G@x + bias + x  (bf16 MFMA, fp32 residual) ----
__global__ __launch_bounds__(512, 2) void k3_apply(const float* __restrict__ x,
                                                   const float* __restrict__ ws,
                                                   float* __restrict__ out) {
  const int wg = (blockIdx.x & 7) * 128 + (blockIdx.x >> 3);  // XCD-bijective swizzle (1024 % 8 == 0)
  const int b = wg >> 6, nt = wg & 63;
  const float* xb = x + (size_t)b*NC*NPIX + (size_t)nt*256;
  const u16* Gb = (const u16*)(ws + O_GB) + (size_t)b*NC*NC;
  const int t = threadIdx.x, lane = t & 63, wid = t >> 6;
  const int wr = wid >> 1, wc = wid & 1;

  __shared__ __align__(16) unsigned char smem[132096]; // 2x(A 32K | B 32K) + bias 1K
  float* bias_lds = (float*)(smem + 131072);
  if (t < 256) bias_lds[t] = ws[O_BIAS + b*NC + t];

  const f32x4 vzero = {0.f, 0.f, 0.f, 0.f};
  u32x4 pa[4];
  f32x4 pb[2][4];
  f32x4 acc[4][8];
  #pragma unroll
  for (int i2 = 0; i2 < 4; ++i2)
    #pragma unroll
    for (int j2 = 0; j2 < 8; ++j2) acc[i2][j2] = vzero;

  auto loadA = [&](int s) {
    const u16* src = Gb + (size_t)(t >> 1)*NC + s*64 + (t & 1)*32;
    #pragma unroll
    for (int j = 0; j < 4; ++j) pa[j] = *(const u32x4*)(src + j*8);
  };
  auto loadB = [&](int s) {
    #pragma unroll
    for (int g = 0; g < 2; ++g) {
      const int id = t + g*512, mc = id >> 6, mn = id & 63;
      const float* src = xb + (size_t)(s*64 + mc*4)*NPIX + mn*4;
      #pragma unroll
      for (int i = 0; i < 4; ++i) pb[g][i] = *(const f32x4*)(src + (size_t)i*NPIX);
    }
  };
  auto storeA = [&](int buf) {
    char* base = (char*)smem + buf*65536;
    const int row = t >> 1, fb = fsw(row);
    #pragma unroll
    for (int j = 0; j < 4; ++j)
      *(u32x4*)(base + row*128 + ((((t & 1)*64) + j*16) ^ fb)) = pa[j];
  };
  auto storeB = [&](int buf) {   // 4x4 micro-transpose: LDS B-tile is [n][c]
    char* base = (char*)smem + buf*65536 + 32768;
    #pragma unroll
    for (int g = 0; g < 2; ++g) {
      const int id = t + g*512, mc = id >> 6, mn = id & 63;
      #pragma unroll
      for (int j = 0; j < 4; ++j) {
        const int row = mn*4 + j;
        u32x2 val;
        val[0] = (unsigned)f2bf(pb[g][0][j]) | ((unsigned)f2bf(pb[g][1][j]) << 16);
        val[1] = (unsigned)f2bf(pb[g][2][j]) | ((unsigned)f2bf(pb[g][3][j]) << 16);
        *(u32x2*)(base + row*128 + ((mc*8) ^ fsw(row))) = val;
      }
    }
  };

  loadA(0); loadB(0);
  storeA(0); storeB(0);
  __syncthreads();
  for (int s = 0; s < 4; ++s) {
    const int cur = s & 1;
    if (s < 3) { loadA(s + 1); loadB(s + 1); }
    const char* Ab = (const char*)smem + cur*65536;
    const char* Bb = (const char*)smem + cur*65536 + 32768;
    #pragma unroll
    for (int kk = 0; kk < 2; ++kk) {
      const int kb = kk*64 + (lane >> 4)*16;
      bf16x8 af[4], bfv[8];
      #pragma unroll
      for (int mi = 0; mi < 4; ++mi) {
        const int row = wr*64 + mi*16 + (lane & 15);
        af[mi] = *(const bf16x8*)(Ab + row*128 + (kb ^ fsw(row)));
      }
      #pragma unroll
      for (int ni = 0; ni < 8; ++ni) {
        const int row = wc*128 + ni*16 + (lane & 15);
        bfv[ni] = *(const bf16x8*)(Bb + row*128 + (kb ^ fsw(row)));
      }
      #pragma unroll
      for (int mi = 0; mi < 4; ++mi)
        #pragma unroll
        for (int ni = 0; ni < 8; ++ni)
          acc[mi][ni] = __builtin_amdgcn_mfma_f32_16x16x32_bf16(af[mi], bfv[ni], acc[mi][ni], 0, 0, 0);
    }
    if (s < 3) { storeA(cur ^ 1); storeB(cur ^ 1); }
    __syncthreads();
  }

  // epilogue: per-wave LDS transpose of acc -> contiguous float4 out; fp32 residual + bias
  float* ep = (float*)smem + wid * (16*132);
  const size_t obase = (size_t)b*NC*NPIX + (size_t)nt*256 + wc*128;
  #pragma unroll
  for (int mi = 0; mi < 4; ++mi) {
    #pragma unroll
    for (int ni = 0; ni < 8; ++ni)
      #pragma unroll
      for (int e = 0; e < 4; ++e)
        ep[((lane >> 4)*4 + e)*132 + ni*16 + (lane & 15)] = acc[mi][ni][e];
    asm volatile("s_waitcnt lgkmcnt(0)" ::: "memory");
    const int o = wr*64 + mi*16 + (lane & 15);
    const float bo = bias_lds[o];
    const float* resp = x + obase + (size_t)o*NPIX + (lane >> 4)*32;
    float* op = out + obase + (size_t)o*NPIX + (lane >> 4)*32;
    #pragma unroll
    for (int j = 0; j < 8; ++j) {
      f32x4 v = *(const f32x4*)(ep + (lane & 15)*132 + (lane >> 4)*32 + j*4);
      const f32x4 r = *(const f32x4*)(resp + j*4);
      v = v + r + bo;
      *(f32x4*)(op + j*4) = v;
    }
  }
}

extern "C" void kernel_launch(void* const* d_in, const int* in_sizes, int n_in,
                              void* d_out, int out_size, void* d_ws, size_t ws_size,
                              hipStream_t stream) {
  const float* x     = (const float*)d_in[0];
  const float* w_in  = (const float*)d_in[1];
  const float* b_in  = (const float*)d_in[2];
  const float* wq    = (const float*)d_in[3];
  const float* bq    = (const float*)d_in[4];
  const float* wk    = (const float*)d_in[5];
  const float* bk    = (const float*)d_in[6];
  const float* wv    = (const float*)d_in[7];
  const float* bv    = (const float*)d_in[8];
  const float* w_out = (const float*)d_in[9];
  const float* b_out = (const float*)d_in[10];
  float* out = (float*)d_out;
  float* ws  = (float*)d_ws;

  // zero Gram + colsum accumulators (ws is poisoned 0xAA before every launch)
  hipMemsetAsync(ws, 0, O_AQ * sizeof(float), stream);
  k0_weights<<<12, 256, 0, stream>>>(w_in, b_in, wq, bq, wk, bk, wv, bv, ws);

  const bool part = ws_size >= (O_GP + GP_FLOATS) * sizeof(float);
  if (part) {
    k1_gram<true><<<256, 512, 0, stream>>>(x, ws);
    k1_reduce<<<1024, 256, 0, stream>>>(ws);
  } else {
    k1_gram<false><<<256, 512, 0, stream>>>(x, ws);  // atomicAdd fallback if ws is small
  }
  k2_s1<<<64, 512, 0, stream>>>(ws);
  k2_score<<<64, 512, 0, stream>>>(ws);
  k2_attn_g<<<64, 512, 0, stream>>>(w_out, b_out, ws);
  k3_apply<<<1024, 512, 0, stream>>>(x, ws, out);
}

// Round 3
// 809.585 us; speedup vs baseline: 1.0287x; 1.0287x over previous
//
#include <hip/hip_runtime.h>

typedef unsigned short u16;
typedef __attribute__((ext_vector_type(4))) float f32x4;
typedef __attribute__((ext_vector_type(4))) unsigned int u32x4;
typedef __attribute__((ext_vector_type(2))) unsigned int u32x2;
typedef __attribute__((ext_vector_type(8))) __bf16 bf16x8;

#define NB 16
#define NC 256
#define ND 64
#define NPIX 16384

// ---- workspace layout (float offsets) ----
static constexpr size_t O_GX   = 0;                               // [16][256][256] f32 Gram
static constexpr size_t O_SX   = O_GX + (size_t)NB*NC*NC;         // [16][256] col sums
static constexpr size_t O_AQ   = O_SX + (size_t)NB*NC;            // Aq [64][256]
static constexpr size_t O_AKT  = O_AQ + (size_t)ND*NC;            // Ak^T [256][64]
static constexpr size_t O_AV   = O_AKT + (size_t)NC*ND;           // Av [64][256]
static constexpr size_t O_BQ   = O_AV + (size_t)ND*NC;            // beta_q [64]
static constexpr size_t O_BK   = O_BQ + ND;
static constexpr size_t O_BV   = O_BK + ND;
static constexpr size_t O_S1   = O_BV + ND;                       // S1 [16][64][256]
static constexpr size_t O_TQ   = O_S1 + (size_t)NB*ND*NC;         // [16][64]
static constexpr size_t O_TK   = O_TQ + (size_t)NB*ND;
static constexpr size_t O_SC   = O_TK + (size_t)NB*ND;            // score [16][64][64]
static constexpr size_t O_BIAS = O_SC + (size_t)NB*ND*ND;         // [16][256]
static constexpr size_t O_GB   = O_BIAS + (size_t)NB*NC;          // G bf16 [16][256][256] (u16)
static constexpr size_t O_GP   = O_GB + (size_t)NB*NC*NC/2;       // Gram partials [16][16][256][256]
static constexpr size_t GP_FLOATS = (size_t)16*NB*NC*NC;

// XOR swizzle on 16B granules within 128B rows
__device__ __forceinline__ int fsw(int row) { return ((row ^ (row >> 3)) & 7) << 4; }

__device__ __forceinline__ u16 f2bf(float f) {      // RNE f32->bf16
  union { float f; unsigned u; } v; v.f = f;
  unsigned r = v.u + 0x7fffu + ((v.u >> 16) & 1u);
  return (u16)(r >> 16);
}

// ---- K0: combined weights  Aq=wq@w_in etc., betas ----
__global__ void k0_weights(const float* __restrict__ w_in, const float* __restrict__ b_in,
                           const float* __restrict__ wq, const float* __restrict__ bqv,
                           const float* __restrict__ wk, const float* __restrict__ bkv,
                           const float* __restrict__ wv, const float* __restrict__ bvv,
                           float* __restrict__ ws) {
  const int m = blockIdx.x >> 2, cc = blockIdx.x & 3;
  const float* w = (m == 0) ? wq : (m == 1) ? wk : wv;
  const int t = threadIdx.x;
  const int i = t >> 2;
  const int c0 = cc*64 + (t & 3)*16;
  float acc[16];
  #pragma unroll
  for (int e = 0; e < 16; ++e) acc[e] = 0.f;
  for (int j = 0; j < 64; ++j) {
    const float wij = w[i*64 + j];
    const float* wr = w_in + (size_t)j*NC + c0;
    #pragma unroll
    for (int e = 0; e < 16; ++e) acc[e] += wij * wr[e];
  }
  if (m == 0)      { float* A = ws + O_AQ;  for (int e = 0; e < 16; ++e) A[(size_t)i*NC + c0 + e] = acc[e]; }
  else if (m == 1) { float* A = ws + O_AKT; for (int e = 0; e < 16; ++e) A[(size_t)(c0+e)*ND + i] = acc[e]; }
  else             { float* A = ws + O_AV;  for (int e = 0; e < 16; ++e) A[(size_t)i*NC + c0 + e] = acc[e]; }
  if (cc == 0 && t < 64) {
    float a = 0.f;
    for (int j = 0; j < 64; ++j) a += w[t*64 + j] * b_in[j];
    a += ((m == 0) ? bqv : (m == 1) ? bkv : bvv)[t];
    ws[((m == 0) ? O_BQ : (m == 1) ? O_BK : O_BV) + t] = a;
  }
}

// ---- K1: per-batch Gram of x (bf16 MFMA). 512 blocks: (b, ks16, colhalf).
// Tile per block: rows 256 x cols 128, K-chunk 1024 px. 8 waves (4 row x 2 col),
// per-wave 64x64 -> acc 64 regs; single 32KB LDS tile, phase-split staging. ----
template<bool PART>
__global__ __launch_bounds__(512, 4) void k1_gram(const float* __restrict__ x, float* __restrict__ ws) {
  // pair halves (r, r+8) -> same XCD so the duplicated x chunk L2-hits
  const int bid = blockIdx.x;
  const int q = bid >> 4, r = bid & 15;
  const int pair = q*8 + (r & 7), half = r >> 3;
  const int b = pair >> 4, ks = pair & 15;
  const float* xb = x + (size_t)b*NC*NPIX + (size_t)ks*1024;

  __shared__ __align__(16) u16 tl[NC*64];   // [c 256][px 64] bf16, swizzled
  const int t = threadIdx.x, lane = t & 63, wid = t >> 6;
  const int wr = wid >> 1, wc = wid & 1;
  const int srow = t >> 2, spx = (t & 3) * 16;

  const f32x4 vzero = {0.f, 0.f, 0.f, 0.f};
  f32x4 acc[4][4];
  #pragma unroll
  for (int i2 = 0; i2 < 4; ++i2)
    #pragma unroll
    for (int j2 = 0; j2 < 4; ++j2) acc[i2][j2] = vzero;
  float csum[2] = {0.f, 0.f};

  for (int it = 0; it < 16; ++it) {
    __syncthreads();   // previous compute done before overwriting tile
    #pragma unroll
    for (int g = 0; g < 2; ++g) {
      const int row = srow + g*128;
      const float* src = xb + (size_t)row*NPIX + it*64 + spx;
      f32x4 ld[4];
      #pragma unroll
      for (int j = 0; j < 4; ++j) ld[j] = *(const f32x4*)(src + j*4);
      u16 h[16]; float s = 0.f;
      #pragma unroll
      for (int j = 0; j < 4; ++j)
        #pragma unroll
        for (int e = 0; e < 4; ++e) { const float v = ld[j][e]; s += v; h[j*4+e] = f2bf(v); }
      csum[g] += s;
      u32x4 w0, w1;
      #pragma unroll
      for (int p = 0; p < 4; ++p) w0[p] = (unsigned)h[2*p]   | ((unsigned)h[2*p+1]   << 16);
      #pragma unroll
      for (int p = 0; p < 4; ++p) w1[p] = (unsigned)h[8+2*p] | ((unsigned)h[8+2*p+1] << 16);
      char* base = (char*)tl + row*128;
      const int fb = fsw(row);
      *(u32x4*)(base + ((spx*2)      ^ fb)) = w0;
      *(u32x4*)(base + ((spx*2 + 16) ^ fb)) = w1;
    }
    __syncthreads();
    #pragma unroll
    for (int kk = 0; kk < 2; ++kk) {
      const int kb = kk*64 + (lane >> 4)*16;
      bf16x8 af[4], bv[4];
      #pragma unroll
      for (int mi = 0; mi < 4; ++mi) {
        const int row = wr*64 + mi*16 + (lane & 15);
        af[mi] = *(const bf16x8*)((const char*)tl + row*128 + (kb ^ fsw(row)));
      }
      #pragma unroll
      for (int ni = 0; ni < 4; ++ni) {
        const int row = half*128 + wc*64 + ni*16 + (lane & 15);
        bv[ni] = *(const bf16x8*)((const char*)tl + row*128 + (kb ^ fsw(row)));
      }
      #pragma unroll
      for (int mi = 0; mi < 4; ++mi)
        #pragma unroll
        for (int ni = 0; ni < 4; ++ni)
          acc[mi][ni] = __builtin_amdgcn_mfma_f32_16x16x32_bf16(af[mi], bv[ni], acc[mi][ni], 0, 0, 0);
    }
  }

  if (half == 0) {   // column sums (one half only; both halves see same rows)
    #pragma unroll
    for (int g = 0; g < 2; ++g) {
      float s = csum[g];
      s += __shfl_xor(s, 1);
      s += __shfl_xor(s, 2);
      if ((t & 3) == 0) atomicAdd(ws + O_SX + b*NC + srow + g*128, s);
    }
  }

  if (PART) {
    float* dst = ws + O_GP + ((size_t)ks*NB + b)*((size_t)NC*NC);
    #pragma unroll
    for (int mi = 0; mi < 4; ++mi)
      #pragma unroll
      for (int ni = 0; ni < 4; ++ni)
        #pragma unroll
        for (int e = 0; e < 4; ++e) {
          const int rr = wr*64 + mi*16 + (lane >> 4)*4 + e;
          const int dd = half*128 + wc*64 + ni*16 + (lane & 15);
          dst[(size_t)rr*NC + dd] = acc[mi][ni][e];
        }
  } else {
    float* dst = ws + O_GX + (size_t)b*NC*NC;
    #pragma unroll
    for (int mi = 0; mi < 4; ++mi)
      #pragma unroll
      for (int ni = 0; ni < 4; ++ni)
        #pragma unroll
        for (int e = 0; e < 4; ++e) {
          const int rr = wr*64 + mi*16 + (lane >> 4)*4 + e;
          const int dd = half*128 + wc*64 + ni*16 + (lane & 15);
          atomicAdd(dst + (size_t)rr*NC + dd, acc[mi][ni][e]);
        }
  }
}

__global__ void k1_reduce(float* __restrict__ ws) {
  const size_t idx = ((size_t)blockIdx.x * 256 + threadIdx.x) * 4;
  const f32x4 vzero = {0.f, 0.f, 0.f, 0.f};
  f32x4 a = vzero;
  #pragma unroll
  for (int ks = 0; ks < 16; ++ks)
    a += *(const f32x4*)(ws + O_GP + (size_t)ks*NB*NC*NC + idx);
  *(f32x4*)(ws + O_GX + idx) = a;
}

// ---- K2a: S1 = Aq @ Gx (fp32) + tq/tk ----
__global__ void k2_s1(float* __restrict__ ws) {
  const int b = blockIdx.x >> 2, jc = blockIdx.x & 3;
  const int t = threadIdx.x;
  const int i = t >> 3, j0 = jc*64 + (t & 7)*8;
  const float* Gx = ws + O_GX + (size_t)b*NC*NC;
  const float* Aq = ws + O_AQ;
  const f32x4 vzero = {0.f, 0.f, 0.f, 0.f};
  f32x4 a0 = vzero, a1 = vzero;
  for (int c = 0; c < 256; ++c) {
    const float a = Aq[(size_t)i*NC + c];
    const float* g = Gx + (size_t)c*NC + j0;
    a0 += a * *(const f32x4*)(g);
    a1 += a * *(const f32x4*)(g + 4);
  }
  float* s1 = ws + O_S1 + (size_t)b*ND*NC + (size_t)i*NC + j0;
  *(f32x4*)(s1) = a0; *(f32x4*)(s1 + 4) = a1;
  if (jc == 0 && t < 128) {
    const float* sxp = ws + O_SX + b*NC;
    float a = 0.f;
    if (t < 64) {
      for (int c = 0; c < 256; ++c) a += ws[O_AKT + (size_t)c*ND + t] * sxp[c];
      ws[O_TK + b*ND + t] = a;
    } else {
      const int i2 = t - 64;
      for (int c = 0; c < 256; ++c) a += ws[O_AQ + (size_t)i2*NC + c] * sxp[c];
      ws[O_TQ + b*ND + i2] = a;
    }
  }
}

// ---- K2b: score = scale*(S1 @ Ak^T + bias cross terms) ----
__global__ void k2_score(float* __restrict__ ws) {
  const int b = blockIdx.x >> 2, jc = blockIdx.x & 3;
  const int t = threadIdx.x;
  const int i = t >> 3, j = jc*16 + (t & 7)*2;
  const float* s1 = ws + O_S1 + (size_t)b*ND*NC + (size_t)i*NC;
  const float* akt = ws + O_AKT;
  float a0 = 0.f, a1 = 0.f;
  for (int d = 0; d < 256; ++d) {
    const float s = s1[d];
    a0 += s * akt[(size_t)d*ND + j];
    a1 += s * akt[(size_t)d*ND + j + 1];
  }
  const float bq = ws[O_BQ + i], tq = ws[O_TQ + b*ND + i];
  const float bk0 = ws[O_BK + j], bk1 = ws[O_BK + j + 1];
  const float tk0 = ws[O_TK + b*ND + j], tk1 = ws[O_TK + b*ND + j + 1];
  const float sc = 0.125f;  // 1/sqrt(64)
  float* so = ws + O_SC + (size_t)b*ND*ND + (size_t)i*ND + j;
  so[0] = sc*(a0 + bq*tk0 + tq*bk0 + 16384.f*bq*bk0);
  so[1] = sc*(a1 + bq*tk1 + tq*bk1 + 16384.f*bq*bk1);
}

// ---- K2c: softmax + M = w_out@attn^T + G = M@Av (bf16) + bias ----
__global__ void k2_attn_g(const float* __restrict__ w_out, const float* __restrict__ b_out,
                          float* __restrict__ ws) {
  const int b = blockIdx.x >> 2, oc = blockIdx.x & 3;
  const int t = threadIdx.x;
  __shared__ float sc[64*68];
  __shared__ float at[64*68];
  __shared__ float ml[64*68];
  #pragma unroll
  for (int k = 0; k < 8; ++k) {
    const int idx = t + k*512;
    sc[(idx >> 6)*68 + (idx & 63)] = ws[O_SC + (size_t)b*ND*ND + idx];
  }
  __syncthreads();
  if (t < 64) {
    float m = -1e30f;
    for (int j = 0; j < 64; ++j) m = fmaxf(m, sc[t*68 + j]);
    float s = 0.f;
    for (int j = 0; j < 64; ++j) { const float e = __expf(sc[t*68 + j] - m); sc[t*68 + j] = e; s += e; }
    const float inv = 1.f / s;
    for (int j = 0; j < 64; ++j) at[j*68 + t] = sc[t*68 + j] * inv;  // attn^T[j][c]
  }
  __syncthreads();
  {
    const int o = t >> 3, c0 = (t & 7)*8;
    float acc[8];
    #pragma unroll
    for (int e = 0; e < 8; ++e) acc[e] = 0.f;
    for (int j = 0; j < 64; ++j) {
      const float w = w_out[(size_t)(oc*64 + o)*ND + j];
      #pragma unroll
      for (int e = 0; e < 8; ++e) acc[e] += w * at[j*68 + c0 + e];
    }
    #pragma unroll
    for (int e = 0; e < 8; ++e) ml[o*68 + c0 + e] = acc[e];
  }
  __syncthreads();
  {
    const int c0 = (t & 15)*16;
    #pragma unroll
    for (int or2 = 0; or2 < 2; ++or2) {
      const int o = (t >> 4) + or2*32;
      float acc[16];
      #pragma unroll
      for (int e = 0; e < 16; ++e) acc[e] = 0.f;
      for (int c = 0; c < 64; ++c) {
        const float m = ml[o*68 + c];
        const float* av = ws + O_AV + (size_t)c*NC + c0;
        #pragma unroll
        for (int e = 0; e < 16; ++e) acc[e] += m * av[e];
      }
      u16* gb = (u16*)(ws + O_GB) + (size_t)b*NC*NC + (size_t)(oc*64 + o)*NC + c0;
      u16 h[16];
      #pragma unroll
      for (int e = 0; e < 16; ++e) h[e] = f2bf(acc[e]);
      u32x4 w0, w1;
      #pragma unroll
      for (int p = 0; p < 4; ++p) w0[p] = (unsigned)h[2*p]   | ((unsigned)h[2*p+1]   << 16);
      #pragma unroll
      for (int p = 0; p < 4; ++p) w1[p] = (unsigned)h[8+2*p] | ((unsigned)h[8+2*p+1] << 16);
      *(u32x4*)(gb) = w0;
      *(u32x4*)(gb + 8) = w1;
    }
  }
  if (t < 64) {
    float a = 0.f;
    for (int c = 0; c < 64; ++c) a += ml[t*68 + c] * ws[O_BV + c];
    ws[O_BIAS + b*NC + oc*64 + t] = a + b_out[oc*64 + t];
  }
}

// ---- K3: out = G@x + bias + x. 4096 blocks (b, 64-px tile), 256 thr (4 waves x 64 rows).
// A (G bf16) fragments read directly from L2-resident global; LDS = 8KB B-tile + bias.
// Target: 4 blocks/CU. Residual re-read is L2-hot (same bytes as B-tile). ----
__global__ __launch_bounds__(256, 4) void k3_apply(const float* __restrict__ x,
                                                   const float* __restrict__ ws,
                                                   float* __restrict__ out) {
  const int bid = blockIdx.x;
  const int b = bid >> 8, nt = bid & 255;
  const float* xb = x + (size_t)b*NC*NPIX + (size_t)nt*64;
  const u16* Gb = (const u16*)(ws + O_GB) + (size_t)b*NC*NC;
  const int t = threadIdx.x, lane = t & 63, w = t >> 6;

  __shared__ __align__(16) u16 blds[64*64];   // [px 64][c 64] bf16, swizzled
  __shared__ float bias_lds[256];
  bias_lds[t] = ws[O_BIAS + b*NC + t];

  const f32x4 vzero = {0.f, 0.f, 0.f, 0.f};
  f32x4 acc[4][4];
  #pragma unroll
  for (int i2 = 0; i2 < 4; ++i2)
    #pragma unroll
    for (int j2 = 0; j2 < 4; ++j2) acc[i2][j2] = vzero;

  for (int s = 0; s < 4; ++s) {
    // ---- stage B: x[s*64..+64 c][nt*64..+64 px] -> LDS [px][c] bf16 (4x4 micro-transpose)
    {
      const int c0 = (t >> 4)*4, px0 = (t & 15)*4;
      f32x4 ld[4];
      #pragma unroll
      for (int j = 0; j < 4; ++j)
        ld[j] = *(const f32x4*)(xb + (size_t)(s*64 + c0 + j)*NPIX + px0);
      __syncthreads();   // previous stage's compute done
      #pragma unroll
      for (int p = 0; p < 4; ++p) {
        const int row = px0 + p;
        u32x2 v;
        v[0] = (unsigned)f2bf(ld[0][p]) | ((unsigned)f2bf(ld[1][p]) << 16);
        v[1] = (unsigned)f2bf(ld[2][p]) | ((unsigned)f2bf(ld[3][p]) << 16);
        *(u32x2*)((char*)blds + row*128 + ((c0*2) ^ fsw(row))) = v;
      }
      __syncthreads();
    }
    // ---- compute: A frags from global (L2), B frags from LDS
    #pragma unroll
    for (int kk = 0; kk < 2; ++kk) {
      bf16x8 af[4], bv[4];
      #pragma unroll
      for (int mi = 0; mi < 4; ++mi) {
        const int row = w*64 + mi*16 + (lane & 15);
        af[mi] = *(const bf16x8*)(Gb + (size_t)row*NC + s*64 + kk*32 + (lane >> 4)*8);
      }
      #pragma unroll
      for (int ni = 0; ni < 4; ++ni) {
        const int row = ni*16 + (lane & 15);
        bv[ni] = *(const bf16x8*)((const char*)blds + row*128 + ((kk*64 + (lane >> 4)*16) ^ fsw(row)));
      }
      #pragma unroll
      for (int mi = 0; mi < 4; ++mi)
        #pragma unroll
        for (int ni = 0; ni < 4; ++ni)
          acc[mi][ni] = __builtin_amdgcn_mfma_f32_16x16x32_bf16(af[mi], bv[ni], acc[mi][ni], 0, 0, 0);
    }
  }

  // ---- epilogue: fp32 residual (L2-hot) + bias, dword stores in 64B segments
  const size_t colbase = (size_t)b*NC*NPIX + (size_t)nt*64;
  #pragma unroll
  for (int mi = 0; mi < 4; ++mi) {
    float bo[4];
    #pragma unroll
    for (int e = 0; e < 4; ++e) bo[e] = bias_lds[w*64 + mi*16 + (lane >> 4)*4 + e];
    #pragma unroll
    for (int ni = 0; ni < 4; ++ni) {
      const int n = ni*16 + (lane & 15);
      #pragma unroll
      for (int e = 0; e < 4; ++e) {
        const int o = w*64 + mi*16 + (lane >> 4)*4 + e;
        const size_t a = colbase + (size_t)o*NPIX + n;
        out[a] = acc[mi][ni][e] + bo[e] + x[a];
      }
    }
  }
}

extern "C" void kernel_launch(void* const* d_in, const int* in_sizes, int n_in,
                              void* d_out, int out_size, void* d_ws, size_t ws_size,
                              hipStream_t stream) {
  const float* x     = (const float*)d_in[0];
  const float* w_in  = (const float*)d_in[1];
  const float* b_in  = (const float*)d_in[2];
  const float* wq    = (const float*)d_in[3];
  const float* bq    = (const float*)d_in[4];
  const float* wk    = (const float*)d_in[5];
  const float* bk    = (const float*)d_in[6];
  const float* wv    = (const float*)d_in[7];
  const float* bv    = (const float*)d_in[8];
  const float* w_out = (const float*)d_in[9];
  const float* b_out = (const float*)d_in[10];
  float* out = (float*)d_out;
  float* ws  = (float*)d_ws;

  const bool part = ws_size >= (O_GP + GP_FLOATS) * sizeof(float);
  if (part) {
    // only the atomic colsum accumulator needs zeroing (k1_reduce overwrites Gx)
    hipMemsetAsync(ws + O_SX, 0, (size_t)NB*NC*sizeof(float), stream);
  } else {
    hipMemsetAsync(ws, 0, O_AQ * sizeof(float), stream);  // Gx + SX
  }
  k0_weights<<<12, 256, 0, stream>>>(w_in, b_in, wq, bq, wk, bk, wv, bv, ws);

  if (part) {
    k1_gram<true><<<512, 512, 0, stream>>>(x, ws);
    k1_reduce<<<1024, 256, 0, stream>>>(ws);
  } else {
    k1_gram<false><<<512, 512, 0, stream>>>(x, ws);  // atomicAdd fallback
  }
  k2_s1<<<64, 512, 0, stream>>>(ws);
  k2_score<<<64, 512, 0, stream>>>(ws);
  k2_attn_g<<<64, 512, 0, stream>>>(w_out, b_out, ws);
  k3_apply<<<4096, 256, 0, stream>>>(x, ws, out);
}